// Round 3
// baseline (272.321 us; speedup 1.0000x reference)
//
#include <hip/hip_runtime.h>

// Problem constants (B=8, S=256, F=16384, K=32)
#define N_ELEMS  33554432   // 8*256*16384
#define N4       8388608    // N_ELEMS/4
#define N_TOKENS 2048
#define F4       4096       // float4 per token
#define K_TOTAL  65536u     // K * B * S
#define NBINS    4096       // fine bins over key range [0xC0000000, 0xC1000000) == f in [2,8)
                            // bin width ~0.001 at cutoff => ~190 elems in cutoff bin

// ws layout (uint32 word indices)
#define C_NG       4096     // gated-list counter
#define C_WINTH    4097     // winner threshold (key >= -> definitely selected)
#define C_CANDTH   4098     // candidate threshold (cutoff-bin lower edge)
#define C_NEED     4099     // how many to take from the cutoff bin
#define C_FB       4100     // fallback flag
#define C_N2       4101     // cutoff-bin candidate counter
#define C_DONE     4102     // k_ghist done-block counter
#define N_CTR_END  4160

#define GLIST_OFF  8192u    // uint2: all gated (f>=2) elements, (key, flat_idx)
#define CAPG       4194304u // expected ~380K; overflow -> fallback
#define LIST2_OFF  (GLIST_OFF + 2u*CAPG)
#define CAP2       4096u    // cutoff-bin candidates (expected ~190)
#define FB1_OFF    16777216u  // fallback scratch lists (correctness-only path)
#define CAPF       2097152u
#define FB2_OFF    (FB1_OFF + 2u*CAPF)

#define GBUF 1024           // per-block LDS staging for compaction
#define GH_BLOCKS 32        // k_ghist grid

// Order-preserving fp32 -> u32 map (larger float <=> larger key)
__device__ __forceinline__ unsigned keyOf(float f) {
    unsigned b = __float_as_uint(f);
    return b ^ ((unsigned)((int)b >> 31) | 0x80000000u);
}
__device__ __forceinline__ float valOf(unsigned u) {
    unsigned b = (u & 0x80000000u) ? (u ^ 0x80000000u) : ~u;
    return __uint_as_float(b);
}
__device__ __forceinline__ unsigned umaxu(unsigned a, unsigned b) { return a > b ? a : b; }

// ---------------- init: zero fine bins + counters (no poison assumptions)
__global__ void k_init(unsigned* __restrict__ ws) {
    int t = blockIdx.x * 256 + threadIdx.x;
    if (t < N_CTR_END) ws[t] = 0u;
}

// ---------------- pass 1 (the ONLY full read of x): PURE stream+compact.
// No histogram work here (that was ~717K contended global atomics across
// 2048 blocks — moved to k_ghist over the compact list). Per token:
// dense-zero output, compact gated (f>=2) elements to glist via LDS staging.
__global__ __launch_bounds__(512) void k_stream(const float4* __restrict__ x,
                                                const int* __restrict__ mask,
                                                unsigned* __restrict__ ws,
                                                float4* __restrict__ out) {
    __shared__ uint2 sbuf[GBUF];       // 8 KB staging for compaction
    __shared__ unsigned s_cnt, s_base;
    const int tok = blockIdx.x;
    const int tid = threadIdx.x;
    float4* ot = out + (size_t)tok * F4;
    const float4 z = make_float4(0.f, 0.f, 0.f, 0.f);
    if (!mask[tok]) {                  // masked token: zero output, no read
        for (int j = tid; j < F4; j += 512) ot[j] = z;
        return;
    }
    if (tid == 0) s_cnt = 0u;
    __syncthreads();
    uint2* glist = (uint2*)(ws + GLIST_OFF);
    const float4* xt = x + (size_t)tok * F4;
    const unsigned baseIdx = (unsigned)tok * 16384u;
    #pragma unroll
    for (int half = 0; half < 2; ++half) {       // 2 chunks of 4 float4/thread
        const int j0 = tid + half * 2048;
        float4 v0 = xt[j0];
        float4 v1 = xt[j0 + 512];
        float4 v2 = xt[j0 + 1024];
        float4 v3 = xt[j0 + 1536];
        ot[j0] = z; ot[j0 + 512] = z; ot[j0 + 1024] = z; ot[j0 + 1536] = z;
        float fv[16] = {v0.x, v0.y, v0.z, v0.w, v1.x, v1.y, v1.z, v1.w,
                        v2.x, v2.y, v2.z, v2.w, v3.x, v3.y, v3.z, v3.w};
        #pragma unroll
        for (int c = 0; c < 16; ++c) {
            float f = fv[c];
            if (f >= 2.0f) {           // ~1-2% of elements; cutoff ~2.66 for this input
                unsigned u = keyOf(f);
                unsigned slot = atomicAdd(&s_cnt, 1u);
                unsigned j = (unsigned)(j0 + (c >> 2) * 512);
                uint2 e = make_uint2(u, baseIdx + j * 4u + (unsigned)(c & 3));
                if (slot < GBUF) sbuf[slot] = e;
                else { unsigned g = atomicAdd(&ws[C_NG], 1u); if (g < CAPG) glist[g] = e; }
            }
        }
    }
    __syncthreads();
    unsigned cnt = s_cnt; if (cnt > GBUF) cnt = GBUF;   // expected ~190-400/block
    if (tid == 0) s_base = atomicAdd(&ws[C_NG], cnt);   // one bulk atomic/block
    __syncthreads();
    for (unsigned j = tid; j < cnt; j += 512) {
        unsigned p = s_base + j;
        if (p < CAPG) glist[p] = sbuf[j];
    }
}

// ---------------- ghist: fine histogram over the COMPACT glist (3 MB, L2-hot)
// with per-block LDS privatization; last-finishing block suffix-scans the bins
// and publishes thresholds + need + fallback flag (so scatter/tail need no scan).
__global__ __launch_bounds__(1024) void k_ghist(unsigned* __restrict__ ws) {
    __shared__ unsigned lh[NBINS];     // 16 KB; reused as scan buffer by last block
    __shared__ unsigned s_last, s_b1, s_ka, s_found;
    const int t = threadIdx.x;
    for (int b = t; b < NBINS; b += 1024) lh[b] = 0u;
    if (t == 0) s_last = 0u;
    __syncthreads();
    const unsigned ngRaw = ws[C_NG];
    unsigned ng = ngRaw > CAPG ? CAPG : ngRaw;
    const uint2* glist = (const uint2*)(ws + GLIST_OFF);
    for (unsigned i = blockIdx.x * 1024u + (unsigned)t; i < ng; i += GH_BLOCKS * 1024u) {
        unsigned u = glist[i].x;       // all glist keys >= keyOf(2.0) = 0xC0000000
        unsigned bin = (u - 0xC0000000u) >> 12;
        if (bin > 4095u) bin = 4095u;  // f>=8 clamps to top bin
        atomicAdd(&lh[bin], 1u);
    }
    __syncthreads();
    for (int b = t; b < NBINS; b += 1024) {
        unsigned c = lh[b];
        if (c) atomicAdd(&ws[b], c);   // ~32*3K merge atomics total (vs 717K before)
    }
    __syncthreads();
    if (t == 0) {
        __threadfence();               // order my merges before the done signal
        unsigned done = atomicAdd(&ws[C_DONE], 1u) + 1u;
        if (done == GH_BLOCKS) s_last = 1u;
    }
    __syncthreads();
    if (!s_last) return;
    // ---- last block: suffix-scan 4096 bins (agent-scope loads: bins were
    // written by device atomics from other XCDs; plain loads could be stale).
    unsigned vv[4]; unsigned s = 0u;
    #pragma unroll
    for (int j = 0; j < 4; ++j) {
        vv[j] = __hip_atomic_load(&ws[t * 4 + j], __ATOMIC_RELAXED, __HIP_MEMORY_SCOPE_AGENT);
        s += vv[j];
    }
    unsigned* sc = lh;                 // reuse (this block's partial hist is dead)
    if (t == 0) s_found = 0u;
    sc[t] = s;
    __syncthreads();
    for (int off = 1; off < 1024; off <<= 1) {
        unsigned a = sc[t];
        unsigned b2 = (t + off < 1024) ? sc[t + off] : 0u;
        __syncthreads();
        sc[t] = a + b2;                // sc[t] = cntGE(bin 4t)
        __syncthreads();
    }
    unsigned run = (t < 1023) ? sc[t + 1] : 0u;      // cntGE(first bin of next chunk)
    #pragma unroll
    for (int j = 3; j >= 0; --j) {
        unsigned prev = run; run += vv[j];           // run = cntGE(bin 4t+j)
        if (run >= K_TOTAL && prev < K_TOTAL) {      // unique crossing
            s_b1 = (unsigned)(t * 4 + j); s_ka = prev; s_found = 1u;
        }
    }
    __syncthreads();
    if (t == 0) {
        unsigned total = sc[0];
        unsigned fb = (s_found == 0u) || (total < K_TOTAL) || (s_b1 == 4095u) || (ngRaw > CAPG);
        ws[C_FB] = fb ? 1u : 0u;
        if (!fb) {
            unsigned candTh = 0xC0000000u + (s_b1 << 12);
            ws[C_CANDTH] = candTh;
            ws[C_WINTH]  = candTh + 0x1000u;
            ws[C_NEED]   = K_TOTAL - s_ka;
        }
    }
}

// ---------------- scatter winners from the compact gated list (no x re-read,
// no scan — thresholds published by k_ghist).
__global__ __launch_bounds__(256) void k_scatter(unsigned* __restrict__ ws,
                                                 float* __restrict__ out) {
    if (ws[C_FB]) return;
    const unsigned winTh = ws[C_WINTH], candTh = ws[C_CANDTH];
    unsigned ng = ws[C_NG]; if (ng > CAPG) ng = CAPG;
    uint2* glist = (uint2*)(ws + GLIST_OFF);
    uint2* list2 = (uint2*)(ws + LIST2_OFF);
    const unsigned stride = gridDim.x * 256u;
    for (unsigned i = blockIdx.x * 256u + (unsigned)threadIdx.x; i < ng; i += stride) {
        uint2 e = glist[i];
        if (e.x >= winTh) out[e.y] = valOf(e.x);     // >= 2.0 > 0: relu moot
        else if (e.x >= candTh) {                    // cutoff bin (~190 total)
            unsigned g = atomicAdd(&ws[C_N2], 1u);
            if (g < CAP2) list2[g] = e;
        }
    }
}

// ---------------- tail + fallback merged (1 block, 1024 threads): fast path =
// exact rank among cutoff-bin candidates + EMA; else full exact fallback.
__global__ __launch_bounds__(1024) void k_tail(const float4* __restrict__ x,
                                               const int* __restrict__ mask,
                                               unsigned* __restrict__ ws,
                                               float* __restrict__ out,
                                               const float* __restrict__ thr) {
    // LDS union: tail ent[4096]uint2 + red[1024] | fb lh[4096]+sred[1024]
    __shared__ __align__(16) unsigned smem[9216];   // 36 KB
    __shared__ unsigned sB1, sKA, sMode, sNegmin, sB2, sNeed, sCnt;
    const int t = threadIdx.x;
    const unsigned rawn2 = ws[C_N2];
    const unsigned fb = ws[C_FB] | (rawn2 > CAP2 ? 1u : 0u);

    if (!fb) {
        // ---- fast tail: exact rank among cutoff-bin candidates + EMA threshold
        uint2* ent = (uint2*)smem;                 // [0, 8192) words
        unsigned* red = smem + 8192;               // [8192, 9216)
        const unsigned n2 = rawn2;
        const unsigned need = ws[C_NEED];          // >= 1 by crossing construction
        uint2* list2 = (uint2*)(ws + LIST2_OFF);
        for (unsigned i = (unsigned)t; i < n2; i += 1024u) ent[i] = list2[i];
        __syncthreads();
        unsigned minSel = 0xFFFFFFFFu;
        for (unsigned i = (unsigned)t; i < n2; i += 1024u) {
            uint2 e = ent[i];
            unsigned rank = 0u;
            for (unsigned j = 0; j < n2; ++j) {    // ties -> lower idx (jax.lax.top_k)
                uint2 o = ent[j];
                rank += (o.x > e.x || (o.x == e.x && o.y < e.y)) ? 1u : 0u;
            }
            if (rank < need) {
                out[e.y] = valOf(e.x);
                if (e.x < minSel) minSel = e.x;
            }
        }
        red[t] = minSel;
        __syncthreads();
        for (int off = 512; off > 0; off >>= 1) {
            if (t < off) red[t] = red[t] < red[t + off] ? red[t] : red[t + off];
            __syncthreads();
        }
        if (t == 0) {
            // fast path: min selected = k-th largest >= 2.0 > 0 == min_pos
            out[N_ELEMS] = 0.99f * thr[0] + 0.01f * valOf(red[0]);
        }
        return;
    }

    // ---- fallback: full exact algorithm (correctness-only; never runs for
    // this input — cutoff >= 2.0 with wide margin). Self-contained.
    unsigned* lh = smem;               // [0, 4096): coarse 12-bit bins then reused
    unsigned* sred = smem + 4096;      // [4096, 5120)
    for (int b = t; b < NBINS; b += 1024) lh[b] = 0u;
    if (t == 0) sCnt = 0u;
    __syncthreads();
    unsigned negmin = 0u;              // max(~key) over positive values
    for (int tok = 0; tok < N_TOKENS; ++tok) {
        if (!mask[tok]) continue;
        const float4* xt = x + (size_t)tok * F4;
        for (int j = t; j < F4; j += 1024) {
            float4 v = xt[j];
            float fv[4] = {v.x, v.y, v.z, v.w};
            #pragma unroll
            for (int c = 0; c < 4; ++c) {
                float f = fv[c];
                unsigned u = keyOf(f);
                atomicAdd(&lh[u >> 20], 1u);
                if (f > 0.0f) negmin = umaxu(negmin, ~u);
            }
        }
    }
    __syncthreads();
    sred[t] = negmin; __syncthreads();
    for (int off = 512; off > 0; off >>= 1) {
        if (t < off) sred[t] = umaxu(sred[t], sred[t + off]);
        __syncthreads();
    }
    if (t == 0) {
        sNegmin = sred[0];
        unsigned tot = 0u;
        for (int b = 0; b < NBINS; ++b) tot += lh[b];
        if (tot <= K_TOTAL) sMode = 1u;          // select ALL unmasked elements
        else {
            sMode = 0u;
            unsigned run = 0u, prev = 0u; int b1 = 0;
            for (int b = NBINS - 1; b >= 0; --b) {
                prev = run; run += lh[b];
                if (run >= K_TOTAL && prev < K_TOTAL) { b1 = b; break; }
            }
            sB1 = (unsigned)b1; sKA = prev;
        }
        sCnt = 0u;
    }
    __syncthreads();
    if (sMode == 1u) {
        for (int tok = 0; tok < N_TOKENS; ++tok) {
            if (!mask[tok]) continue;
            const float4* xt = x + (size_t)tok * F4;
            float* ot = out + (size_t)tok * 16384;
            for (int j = t; j < F4; j += 1024) {
                float4 v = xt[j];
                ot[j * 4 + 0] = fmaxf(v.x, 0.f); ot[j * 4 + 1] = fmaxf(v.y, 0.f);
                ot[j * 4 + 2] = fmaxf(v.z, 0.f); ot[j * 4 + 3] = fmaxf(v.w, 0.f);
            }
        }
        if (t == 0) {
            float th = thr[0], newt = th;
            if (sNegmin) newt = 0.99f * th + 0.01f * valOf(~sNegmin);
            out[N_ELEMS] = newt;
        }
        return;
    }
    // phase 2: scatter coarse winners; compact coarse cutoff bin
    const unsigned B1c = sB1;
    uint2* fb1 = (uint2*)(ws + FB1_OFF);
    for (int tok = 0; tok < N_TOKENS; ++tok) {
        if (!mask[tok]) continue;
        const float4* xt = x + (size_t)tok * F4;
        const unsigned baseIdx = (unsigned)tok * 16384u;
        for (int j = t; j < F4; j += 1024) {
            float4 v = xt[j];
            float fv[4] = {v.x, v.y, v.z, v.w};
            #pragma unroll
            for (int c = 0; c < 4; ++c) {
                float f = fv[c];
                unsigned u = keyOf(f);
                unsigned p = u >> 20;
                unsigned idx = baseIdx + (unsigned)j * 4u + (unsigned)c;
                if (p > B1c) out[idx] = fmaxf(f, 0.f);
                else if (p == B1c) {
                    unsigned g = atomicAdd(&sCnt, 1u);
                    if (g < CAPF) fb1[g] = make_uint2(u, idx);
                }
            }
        }
    }
    __syncthreads();
    unsigned n1 = sCnt > CAPF ? CAPF : sCnt;
    __syncthreads();
    if (t < 256) lh[t] = 0u;           // reuse as 8-bit refine histogram
    if (t == 0) sCnt = 0u;
    __syncthreads();
    for (unsigned i = t; i < n1; i += 1024)
        atomicAdd(&lh[(fb1[i].x >> 12) & 255u], 1u);
    __syncthreads();
    if (t == 0) {
        unsigned run = sKA, prev = sKA; int b2 = 0;
        for (int b = 255; b >= 0; --b) {
            prev = run; run += lh[b];
            if (run >= K_TOTAL) { b2 = b; break; }
        }
        sB2 = (unsigned)b2; sNeed = K_TOTAL - prev;
    }
    __syncthreads();
    const unsigned B2 = sB2, need = sNeed;
    uint2* fb2 = (uint2*)(ws + FB2_OFF);
    for (unsigned i = t; i < n1; i += 1024) {
        uint2 e = fb1[i];
        unsigned bb = (e.x >> 12) & 255u;
        if (bb > B2) out[e.y] = fmaxf(valOf(e.x), 0.f);
        else if (bb == B2) {
            unsigned g = atomicAdd(&sCnt, 1u);
            if (g < CAPF) fb2[g] = e;
        }
    }
    __syncthreads();
    unsigned n2 = sCnt > CAPF ? CAPF : sCnt;
    unsigned minSel = 0xFFFFFFFFu;
    for (unsigned i = t; i < n2; i += 1024) {
        uint2 e = fb2[i];
        unsigned rank = 0u;
        for (unsigned jj = 0; jj < n2; ++jj) {
            uint2 o = fb2[jj];
            rank += (o.x > e.x || (o.x == e.x && o.y < e.y)) ? 1u : 0u;
        }
        if (rank < need) { out[e.y] = fmaxf(valOf(e.x), 0.f); if (e.x < minSel) minSel = e.x; }
    }
    __syncthreads();
    sred[t] = minSel; __syncthreads();
    for (int off = 512; off > 0; off >>= 1) {
        if (t < off) sred[t] = sred[t] < sred[t + off] ? sred[t] : sred[t + off];
        __syncthreads();
    }
    if (t == 0) {
        float th = thr[0], newt = th;
        unsigned vku = sred[0];
        if (vku != 0xFFFFFFFFu) {
            float vk = valOf(vku);
            float minpos; int any;
            if (vk > 0.f) { minpos = vk; any = 1; }
            else { any = (sNegmin != 0u); minpos = any ? valOf(~sNegmin) : 0.f; }
            if (any) newt = 0.99f * th + 0.01f * minpos;
        }
        out[N_ELEMS] = newt;
    }
}

extern "C" void kernel_launch(void* const* d_in, const int* in_sizes, int n_in,
                              void* d_out, int out_size, void* d_ws, size_t ws_size,
                              hipStream_t stream) {
    const float4* x  = (const float4*)d_in[0];
    const int* mask  = (const int*)d_in[1];
    const float* thr = (const float*)d_in[2];
    float* out       = (float*)d_out;
    unsigned* ws     = (unsigned*)d_ws;

    k_init    <<<17, 256, 0, stream>>>(ws);
    k_stream  <<<N_TOKENS, 512, 0, stream>>>(x, mask, ws, (float4*)out);
    k_ghist   <<<GH_BLOCKS, 1024, 0, stream>>>(ws);
    k_scatter <<<256, 256, 0, stream>>>(ws, out);
    k_tail    <<<1, 1024, 0, stream>>>(x, mask, ws, out, thr);
}

// Round 4
// 272.092 us; speedup vs baseline: 1.0008x; 1.0008x over previous
//
#include <hip/hip_runtime.h>

// Problem constants (B=8, S=256, F=16384, K=32)
#define N_ELEMS  33554432   // 8*256*16384
#define N_TOKENS 2048
#define F4       4096       // float4 per token
#define K_TOTAL  65536u     // K * B * S
#define NBINS    4096       // fine bins over key range [0xC0000000, 0xC1000000) == f in [2,8)

// ws layout (uint32 word indices)
#define C_NG       4096     // gated-list counter
#define C_WINTH    4097     // winner threshold (key >= -> definitely selected)
#define C_CANDTH   4098     // candidate threshold (cutoff-bin lower edge)
#define C_NEED     4099     // how many to take from the cutoff bin
#define C_FB       4100     // fallback flag
#define C_N2       4101     // cutoff-bin candidate counter
#define C_DONE     4102     // k_ghist done-block counter
#define C_PK       4107     // pivot key   (k-th largest overall)
#define C_PIDX     4108     // pivot flat idx (tie-break: lower idx wins)
#define C_DONE2    4109     // k_candpivot done-block counter
#define N_CTR_END  4160

#define SEG_OFF    4608u    // per-token segment table: [2*tok]=base, [2*tok+1]=cnt (4096 words)
#define GLIST_OFF  16384u   // uint2: all gated (f>=2) elements, (key, flat_idx), per-token contiguous
#define CAPG       4194304u // expected ~380K; overflow -> fallback
#define LIST2_OFF  (GLIST_OFF + 2u*CAPG)
#define CAP2       4096u    // cutoff-bin candidates (expected ~190)
#define FB1_OFF    16777216u  // fallback scratch lists (correctness-only path)
#define CAPF       2097152u
#define FB2_OFF    (FB1_OFF + 2u*CAPF)

#define GBUF 1024           // per-token LDS staging (per-token gated cnt > GBUF -> fallback)
#define GH_BLOCKS 32        // k_ghist grid
#define CP_BLOCKS 64        // k_candpivot grid

// Order-preserving fp32 -> u32 map (larger float <=> larger key)
__device__ __forceinline__ unsigned keyOf(float f) {
    unsigned b = __float_as_uint(f);
    return b ^ ((unsigned)((int)b >> 31) | 0x80000000u);
}
__device__ __forceinline__ float valOf(unsigned u) {
    unsigned b = (u & 0x80000000u) ? (u ^ 0x80000000u) : ~u;
    return __uint_as_float(b);
}
__device__ __forceinline__ unsigned umaxu(unsigned a, unsigned b) { return a > b ? a : b; }

// ---------------- init: zero fine bins + counters (no poison assumptions)
__global__ void k_init(unsigned* __restrict__ ws) {
    int t = blockIdx.x * 256 + threadIdx.x;
    if (t < N_CTR_END) ws[t] = 0u;
}

// ---------------- gate: PURE READ pass (the only full read of x).
// Per token block: compact gated (f>=2) elements into the token's contiguous
// glist segment via LDS staging; publish (base,cnt) in the seg table.
// NO writes to out here (emit handles the dense zeros as a pure write stream).
__global__ __launch_bounds__(512) void k_gate(const float4* __restrict__ x,
                                              const int* __restrict__ mask,
                                              unsigned* __restrict__ ws) {
    __shared__ uint2 sbuf[GBUF];       // 8 KB staging
    __shared__ unsigned s_cnt, s_base;
    const int tok = blockIdx.x;
    const int tid = threadIdx.x;
    if (!mask[tok]) {                  // masked token: empty segment, no read
        if (tid == 0) { ws[SEG_OFF + 2u*tok] = 0u; ws[SEG_OFF + 2u*tok + 1u] = 0u; }
        return;
    }
    if (tid == 0) s_cnt = 0u;
    __syncthreads();
    const float4* xt = x + (size_t)tok * F4;
    const unsigned baseIdx = (unsigned)tok * 16384u;
    #pragma unroll
    for (int half = 0; half < 2; ++half) {       // 2 chunks of 4 float4/thread
        const int j0 = tid + half * 2048;
        float4 v0 = xt[j0];
        float4 v1 = xt[j0 + 512];
        float4 v2 = xt[j0 + 1024];
        float4 v3 = xt[j0 + 1536];
        float fv[16] = {v0.x, v0.y, v0.z, v0.w, v1.x, v1.y, v1.z, v1.w,
                        v2.x, v2.y, v2.z, v2.w, v3.x, v3.y, v3.z, v3.w};
        #pragma unroll
        for (int c = 0; c < 16; ++c) {
            float f = fv[c];
            if (f >= 2.0f) {           // ~1-2% of elements; cutoff ~2.66 for this input
                unsigned u = keyOf(f);
                unsigned slot = atomicAdd(&s_cnt, 1u);
                unsigned j = (unsigned)(j0 + (c >> 2) * 512);
                if (slot < GBUF) sbuf[slot] = make_uint2(u, baseIdx + j * 4u + (unsigned)(c & 3));
                // slot >= GBUF: dropped; detected below -> fallback recomputes from x
            }
        }
    }
    __syncthreads();
    unsigned cnt = s_cnt;
    const bool ovf = cnt > GBUF;
    if (ovf) cnt = GBUF;
    if (tid == 0) {
        unsigned b = atomicAdd(&ws[C_NG], cnt);  // one bulk atomic/token
        s_base = b;
        ws[SEG_OFF + 2u*tok] = b;
        ws[SEG_OFF + 2u*tok + 1u] = cnt;
        if (ovf) atomicOr(&ws[C_FB], 1u);        // pathological token -> exact fallback
    }
    __syncthreads();
    uint2* glist = (uint2*)(ws + GLIST_OFF);
    const unsigned b0 = s_base;
    for (unsigned j = tid; j < cnt; j += 512u) {
        unsigned p = b0 + j;
        if (p < CAPG) glist[p] = sbuf[j];        // C_NG>CAPG caught in k_ghist -> fallback
    }
}

// ---------------- ghist: fine histogram over the COMPACT glist (3 MB, cache-hot)
// with per-block LDS privatization; last-finishing block suffix-scans the bins
// and publishes thresholds + need + fallback flag.
__global__ __launch_bounds__(1024) void k_ghist(unsigned* __restrict__ ws) {
    __shared__ unsigned lh[NBINS];     // 16 KB; reused as scan buffer by last block
    __shared__ unsigned s_last, s_b1, s_ka, s_found;
    const int t = threadIdx.x;
    for (int b = t; b < NBINS; b += 1024) lh[b] = 0u;
    if (t == 0) s_last = 0u;
    __syncthreads();
    const unsigned ngRaw = ws[C_NG];
    unsigned ng = ngRaw > CAPG ? CAPG : ngRaw;
    const uint2* glist = (const uint2*)(ws + GLIST_OFF);
    for (unsigned i = blockIdx.x * 1024u + (unsigned)t; i < ng; i += GH_BLOCKS * 1024u) {
        unsigned u = glist[i].x;       // all glist keys >= keyOf(2.0) = 0xC0000000
        unsigned bin = (u - 0xC0000000u) >> 12;
        if (bin > 4095u) bin = 4095u;  // f>=8 clamps to top bin
        atomicAdd(&lh[bin], 1u);
    }
    __syncthreads();
    for (int b = t; b < NBINS; b += 1024) {
        unsigned c = lh[b];
        if (c) atomicAdd(&ws[b], c);
    }
    __syncthreads();
    if (t == 0) {
        __threadfence();               // order my merges before the done signal
        unsigned done = atomicAdd(&ws[C_DONE], 1u) + 1u;
        if (done == GH_BLOCKS) s_last = 1u;
    }
    __syncthreads();
    if (!s_last) return;
    // ---- last block: suffix-scan 4096 bins (agent-scope loads: bins were
    // written by device atomics from other XCDs).
    unsigned vv[4]; unsigned s = 0u;
    #pragma unroll
    for (int j = 0; j < 4; ++j) {
        vv[j] = __hip_atomic_load(&ws[t * 4 + j], __ATOMIC_RELAXED, __HIP_MEMORY_SCOPE_AGENT);
        s += vv[j];
    }
    unsigned* sc = lh;                 // reuse (this block's partial hist is dead)
    if (t == 0) s_found = 0u;
    sc[t] = s;
    __syncthreads();
    for (int off = 1; off < 1024; off <<= 1) {
        unsigned a = sc[t];
        unsigned b2 = (t + off < 1024) ? sc[t + off] : 0u;
        __syncthreads();
        sc[t] = a + b2;                // sc[t] = cntGE(bin 4t)
        __syncthreads();
    }
    unsigned run = (t < 1023) ? sc[t + 1] : 0u;      // cntGE(first bin of next chunk)
    #pragma unroll
    for (int j = 3; j >= 0; --j) {
        unsigned prev = run; run += vv[j];           // run = cntGE(bin 4t+j)
        if (run >= K_TOTAL && prev < K_TOTAL) {      // unique crossing
            s_b1 = (unsigned)(t * 4 + j); s_ka = prev; s_found = 1u;
        }
    }
    __syncthreads();
    if (t == 0) {
        unsigned total = sc[0];
        unsigned prevFB = __hip_atomic_load(&ws[C_FB], __ATOMIC_RELAXED, __HIP_MEMORY_SCOPE_AGENT);
        unsigned fb = prevFB | ((s_found == 0u) || (total < K_TOTAL) ||
                                (s_b1 == 4095u) || (ngRaw > CAPG) ? 1u : 0u);
        ws[C_FB] = fb;
        if (!fb) {
            unsigned candTh = 0xC0000000u + (s_b1 << 12);
            ws[C_CANDTH] = candTh;
            ws[C_WINTH]  = candTh + 0x1000u;
            ws[C_NEED]   = K_TOTAL - s_ka;
        }
    }
}

// ---------------- candpivot: collect cutoff-bin candidates from glist; the
// last-finishing block computes the exact PIVOT = k-th largest (key,idx) pair
// under (key desc, idx asc), publishes it, and writes the EMA threshold.
// Selection then reduces to a per-entry predicate in k_emit (no re-scatter).
__global__ __launch_bounds__(256) void k_candpivot(unsigned* __restrict__ ws,
                                                   float* __restrict__ out,
                                                   const float* __restrict__ thr) {
    __shared__ __align__(16) uint2 ent[CAP2];  // 32 KB
    __shared__ unsigned s_last, s_pk, s_pidx;
    const int t = threadIdx.x;
    if (ws[C_FB]) return;
    const unsigned winTh = ws[C_WINTH], candTh = ws[C_CANDTH];
    unsigned ng = ws[C_NG]; if (ng > CAPG) ng = CAPG;
    const uint2* glist = (const uint2*)(ws + GLIST_OFF);
    uint2* list2 = (uint2*)(ws + LIST2_OFF);
    if (t == 0) s_last = 0u;
    for (unsigned i = blockIdx.x * 256u + (unsigned)t; i < ng; i += CP_BLOCKS * 256u) {
        uint2 e = glist[i];
        if (e.x >= candTh && e.x < winTh) {          // cutoff bin (~190 total)
            unsigned g = atomicAdd(&ws[C_N2], 1u);
            if (g < CAP2) list2[g] = e;
        }
    }
    __syncthreads();
    if (t == 0) {
        __threadfence();
        unsigned done = atomicAdd(&ws[C_DONE2], 1u) + 1u;
        if (done == CP_BLOCKS) s_last = 1u;
    }
    __syncthreads();
    if (!s_last) return;
    // ---- last block: exact pivot among <=CAP2 candidates
    unsigned n2 = __hip_atomic_load(&ws[C_N2], __ATOMIC_RELAXED, __HIP_MEMORY_SCOPE_AGENT);
    if (n2 > CAP2) { if (t == 0) ws[C_FB] = 1u; return; }
    const unsigned need = ws[C_NEED];          // 1 <= need <= n2 by crossing construction
    unsigned* l2w = ws + LIST2_OFF;
    for (unsigned i = (unsigned)t; i < n2; i += 256u) {   // agent loads: cross-XCD writes
        unsigned kx = __hip_atomic_load(&l2w[2u*i],     __ATOMIC_RELAXED, __HIP_MEMORY_SCOPE_AGENT);
        unsigned ix = __hip_atomic_load(&l2w[2u*i + 1u], __ATOMIC_RELAXED, __HIP_MEMORY_SCOPE_AGENT);
        ent[i] = make_uint2(kx, ix);
    }
    __syncthreads();
    for (unsigned i = (unsigned)t; i < n2; i += 256u) {
        uint2 e = ent[i];
        unsigned rank = 0u;
        for (unsigned j = 0; j < n2; ++j) {    // ties -> lower idx (jax.lax.top_k)
            uint2 o = ent[j];
            rank += (o.x > e.x || (o.x == e.x && o.y < e.y)) ? 1u : 0u;
        }
        if (rank == need - 1u) { s_pk = e.x; s_pidx = e.y; }   // unique
    }
    __syncthreads();
    if (t == 0) {
        ws[C_PK] = s_pk; ws[C_PIDX] = s_pidx;
        // min selected value == pivot value (k-th largest), >= 2.0 > 0 => == min_pos
        out[N_ELEMS] = 0.99f * thr[0] + 0.01f * valOf(s_pk);
    }
}

// ---------------- emit: PURE WRITE pass. Per token: load its glist segment
// (cache-hot), stream dense zeros, then patch winners (e > pivot lex) into
// lines this block just zeroed (same-XCD L2-hot). On fallback: zeros only
// (fallback overwrites winners + EMA afterwards).
__global__ __launch_bounds__(512) void k_emit(unsigned* __restrict__ ws,
                                              float4* __restrict__ out) {
    __shared__ uint2 ent[GBUF];        // 8 KB
    const int tok = blockIdx.x;
    const int tid = threadIdx.x;
    const unsigned fb = ws[C_FB];
    unsigned cnt = fb ? 0u : ws[SEG_OFF + 2u*tok + 1u];
    const unsigned base = ws[SEG_OFF + 2u*tok];
    const unsigned pk   = ws[C_PK];
    const unsigned pidx = ws[C_PIDX];
    const uint2* glist = (const uint2*)(ws + GLIST_OFF);
    for (unsigned i = (unsigned)tid; i < cnt; i += 512u) {
        unsigned p = base + i;
        ent[i] = (p < CAPG) ? glist[p] : make_uint2(0u, 0u);
    }
    float4* ot = out + (size_t)tok * F4;
    const float4 z = make_float4(0.f, 0.f, 0.f, 0.f);
    #pragma unroll
    for (int half = 0; half < 2; ++half) {
        const int j0 = tid + half * 2048;
        ot[j0] = z; ot[j0 + 512] = z; ot[j0 + 1024] = z; ot[j0 + 1536] = z;
    }
    __syncthreads();                   // drains zero stores (vmcnt0 before barrier)
    float* of = (float*)out;
    for (unsigned i = (unsigned)tid; i < cnt; i += 512u) {
        uint2 e = ent[i];
        if (e.x > pk || (e.x == pk && e.y <= pidx))   // selected (lex >= pivot)
            of[e.y] = valOf(e.x);
    }
}

// ---------------- fallback: full exact algorithm, single block (correctness-
// only; never runs for this input — cutoff >= 2.0 with wide margin).
// Background zeros are guaranteed by k_emit's zeros-only mode.
__global__ __launch_bounds__(1024) void k_fallback(const float4* __restrict__ x,
                                                   const int* __restrict__ mask,
                                                   unsigned* __restrict__ ws,
                                                   float* __restrict__ out,
                                                   const float* __restrict__ thr) {
    if (ws[C_FB] == 0u) return;
    __shared__ unsigned lh[NBINS];     // 16 KB, coarse 12-bit bins then reused
    __shared__ unsigned sred[1024];
    __shared__ unsigned sB1, sKA, sMode, sNegmin, sB2, sNeed, sCnt;
    const int t = threadIdx.x;
    for (int b = t; b < NBINS; b += 1024) lh[b] = 0u;
    if (t == 0) sCnt = 0u;
    __syncthreads();
    unsigned negmin = 0u;              // max(~key) over positive values
    for (int tok = 0; tok < N_TOKENS; ++tok) {
        if (!mask[tok]) continue;
        const float4* xt = x + (size_t)tok * F4;
        for (int j = t; j < F4; j += 1024) {
            float4 v = xt[j];
            float fv[4] = {v.x, v.y, v.z, v.w};
            #pragma unroll
            for (int c = 0; c < 4; ++c) {
                float f = fv[c];
                unsigned u = keyOf(f);
                atomicAdd(&lh[u >> 20], 1u);
                if (f > 0.0f) negmin = umaxu(negmin, ~u);
            }
        }
    }
    __syncthreads();
    sred[t] = negmin; __syncthreads();
    for (int off = 512; off > 0; off >>= 1) {
        if (t < off) sred[t] = umaxu(sred[t], sred[t + off]);
        __syncthreads();
    }
    if (t == 0) {
        sNegmin = sred[0];
        unsigned tot = 0u;
        for (int b = 0; b < NBINS; ++b) tot += lh[b];
        if (tot <= K_TOTAL) sMode = 1u;          // select ALL unmasked elements
        else {
            sMode = 0u;
            unsigned run = 0u, prev = 0u; int b1 = 0;
            for (int b = NBINS - 1; b >= 0; --b) {
                prev = run; run += lh[b];
                if (run >= K_TOTAL && prev < K_TOTAL) { b1 = b; break; }
            }
            sB1 = (unsigned)b1; sKA = prev;
        }
        sCnt = 0u;
    }
    __syncthreads();
    if (sMode == 1u) {
        for (int tok = 0; tok < N_TOKENS; ++tok) {
            if (!mask[tok]) continue;
            const float4* xt = x + (size_t)tok * F4;
            float* ot = out + (size_t)tok * 16384;
            for (int j = t; j < F4; j += 1024) {
                float4 v = xt[j];
                ot[j * 4 + 0] = fmaxf(v.x, 0.f); ot[j * 4 + 1] = fmaxf(v.y, 0.f);
                ot[j * 4 + 2] = fmaxf(v.z, 0.f); ot[j * 4 + 3] = fmaxf(v.w, 0.f);
            }
        }
        if (t == 0) {
            float th = thr[0], newt = th;
            if (sNegmin) newt = 0.99f * th + 0.01f * valOf(~sNegmin);
            out[N_ELEMS] = newt;
        }
        return;
    }
    // phase 2: scatter coarse winners; compact coarse cutoff bin
    const unsigned B1c = sB1;
    uint2* fb1 = (uint2*)(ws + FB1_OFF);
    for (int tok = 0; tok < N_TOKENS; ++tok) {
        if (!mask[tok]) continue;
        const float4* xt = x + (size_t)tok * F4;
        const unsigned baseIdx = (unsigned)tok * 16384u;
        for (int j = t; j < F4; j += 1024) {
            float4 v = xt[j];
            float fv[4] = {v.x, v.y, v.z, v.w};
            #pragma unroll
            for (int c = 0; c < 4; ++c) {
                float f = fv[c];
                unsigned u = keyOf(f);
                unsigned p = u >> 20;
                unsigned idx = baseIdx + (unsigned)j * 4u + (unsigned)c;
                if (p > B1c) out[idx] = fmaxf(f, 0.f);
                else if (p == B1c) {
                    unsigned g = atomicAdd(&sCnt, 1u);
                    if (g < CAPF) fb1[g] = make_uint2(u, idx);
                }
            }
        }
    }
    __syncthreads();
    unsigned n1 = sCnt > CAPF ? CAPF : sCnt;
    __syncthreads();
    if (t < 256) lh[t] = 0u;           // reuse as 8-bit refine histogram
    if (t == 0) sCnt = 0u;
    __syncthreads();
    for (unsigned i = t; i < n1; i += 1024)
        atomicAdd(&lh[(fb1[i].x >> 12) & 255u], 1u);
    __syncthreads();
    if (t == 0) {
        unsigned run = sKA, prev = sKA; int b2 = 0;
        for (int b = 255; b >= 0; --b) {
            prev = run; run += lh[b];
            if (run >= K_TOTAL) { b2 = b; break; }
        }
        sB2 = (unsigned)b2; sNeed = K_TOTAL - prev;
    }
    __syncthreads();
    const unsigned B2 = sB2, need = sNeed;
    uint2* fb2 = (uint2*)(ws + FB2_OFF);
    for (unsigned i = t; i < n1; i += 1024) {
        uint2 e = fb1[i];
        unsigned bb = (e.x >> 12) & 255u;
        if (bb > B2) out[e.y] = fmaxf(valOf(e.x), 0.f);
        else if (bb == B2) {
            unsigned g = atomicAdd(&sCnt, 1u);
            if (g < CAPF) fb2[g] = e;
        }
    }
    __syncthreads();
    unsigned n2 = sCnt > CAPF ? CAPF : sCnt;
    unsigned minSel = 0xFFFFFFFFu;
    for (unsigned i = t; i < n2; i += 1024) {
        uint2 e = fb2[i];
        unsigned rank = 0u;
        for (unsigned jj = 0; jj < n2; ++jj) {
            uint2 o = fb2[jj];
            rank += (o.x > e.x || (o.x == e.x && o.y < e.y)) ? 1u : 0u;
        }
        if (rank < need) { out[e.y] = fmaxf(valOf(e.x), 0.f); if (e.x < minSel) minSel = e.x; }
    }
    __syncthreads();
    sred[t] = minSel; __syncthreads();
    for (int off = 512; off > 0; off >>= 1) {
        if (t < off) sred[t] = sred[t] < sred[t + off] ? sred[t] : sred[t + off];
        __syncthreads();
    }
    if (t == 0) {
        float th = thr[0], newt = th;
        unsigned vku = sred[0];
        if (vku != 0xFFFFFFFFu) {
            float vk = valOf(vku);
            float minpos; int any;
            if (vk > 0.f) { minpos = vk; any = 1; }
            else { any = (sNegmin != 0u); minpos = any ? valOf(~sNegmin) : 0.f; }
            if (any) newt = 0.99f * th + 0.01f * minpos;
        }
        out[N_ELEMS] = newt;
    }
}

extern "C" void kernel_launch(void* const* d_in, const int* in_sizes, int n_in,
                              void* d_out, int out_size, void* d_ws, size_t ws_size,
                              hipStream_t stream) {
    const float4* x  = (const float4*)d_in[0];
    const int* mask  = (const int*)d_in[1];
    const float* thr = (const float*)d_in[2];
    float* out       = (float*)d_out;
    unsigned* ws     = (unsigned*)d_ws;

    k_init      <<<17, 256, 0, stream>>>(ws);
    k_gate      <<<N_TOKENS, 512, 0, stream>>>(x, mask, ws);
    k_ghist     <<<GH_BLOCKS, 1024, 0, stream>>>(ws);
    k_candpivot <<<CP_BLOCKS, 256, 0, stream>>>(ws, out, thr);
    k_emit      <<<N_TOKENS, 512, 0, stream>>>(ws, (float4*)out);
    k_fallback  <<<1, 1024, 0, stream>>>(x, mask, ws, out, thr);
}